// Round 1
// baseline (333.415 us; speedup 1.0000x reference)
//
#include <hip/hip_runtime.h>
#include <hip/hip_bf16.h>
#include <math.h>

#define NT 32
#define NSTEP 31
#define DD 384
#define HH 128
#define KK 128
#define MBATCH 8
#define NPIX 65536   // 256*256

// ---------------- DPP row reductions (VALU-only, no LDS pipe) ----------------
template<int CTRL>
__device__ __forceinline__ float dpp_add(float v) {
  int m = __builtin_amdgcn_update_dpp(0, __float_as_int(v), CTRL, 0xf, 0xf, true);
  return v + __int_as_float(m);
}
// sum across 16 consecutive lanes (one DPP row); every lane gets the sum
__device__ __forceinline__ float red16(float v) {
  v = dpp_add<0xB1>(v);   // quad_perm(1,0,3,2)  xor 1
  v = dpp_add<0x4E>(v);   // quad_perm(2,3,0,1)  xor 2
  v = dpp_add<0x141>(v);  // row_half_mirror     xor 4 (within 8)
  v = dpp_add<0x140>(v);  // row_mirror          xor 8 (within 16)
  return v;
}
// sum across 8 consecutive lanes (half row)
__device__ __forceinline__ float red8(float v) {
  v = dpp_add<0xB1>(v);
  v = dpp_add<0x4E>(v);
  v = dpp_add<0x141>(v);
  return v;
}

// ---------------- Kernel 1: serial RK4 (3/8 rule) ODE, 1 block --------------
// All MB rows of y are identical (y0 = tile(init_coeffs), MLP row-independent)
// so we integrate ONE D=384 state. Weights live in VGPRs (224 floats/lane).
__global__ __launch_bounds__(512, 2) void ode_kernel(
    const float* __restrict__ tarr, const float* __restrict__ ic,
    const float* __restrict__ W1, const float* __restrict__ b1,
    const float* __restrict__ W2, const float* __restrict__ b2,
    const float* __restrict__ W3, const float* __restrict__ b3,
    float* __restrict__ coeffT)   // [3][128][32] = [c][k][t]
{
  __shared__ __align__(16) float sh_x[DD];
  __shared__ __align__(16) float sh_h1[HH];
  __shared__ __align__(16) float sh_h2[HH];
  __shared__ __align__(16) float sh_k[4][DD];
  __shared__ __align__(16) float sh_y[DD];
  __shared__ __align__(16) float sh_b1[HH];
  __shared__ __align__(16) float sh_b2[HH];
  __shared__ __align__(16) float sh_b3[DD];
  __shared__ float sh_t[NT];

  const int tid = threadIdx.x;
  const int w   = tid >> 6;   // wave 0..7
  const int l   = tid & 63;   // lane

  if (tid < HH) { sh_b1[tid] = b1[tid]; sh_b2[tid] = b2[tid]; }
  if (tid < DD) {
    sh_b3[tid] = b3[tid];
    float y0 = ic[tid];
    sh_y[tid] = y0;
    coeffT[(tid % 3) * (KK * NT) + (tid / 3) * NT + 0] = y0;  // t = 0
  }
  if (tid < NT) sh_t[tid] = tarr[tid];

  // ---- per-lane weight residency ----
  // L1 (384->128): wave owns 16 outputs; lane: jg=l>>4 -> 4 outputs,
  //                il=l&15 -> 24 inputs. 96 weights.
  // L2 (128->128): same j mapping; il -> 8 inputs. 32 weights.
  // L3 (128->384): wave owns 48 outputs; jg3=l>>3 -> 6 outputs,
  //                il3=l&7 -> 16 inputs. 96 weights.
  const int jg  = l >> 4, il  = l & 15;
  const int jg3 = l >> 3, il3 = l & 7;
  const int j1 = w * 16 + jg * 4;
  const int j3 = w * 48 + jg3 * 6;

  float w1r[96], w2r[32], w3r[96];
  #pragma unroll
  for (int o = 0; o < 4; ++o)
    #pragma unroll
    for (int ii = 0; ii < 24; ++ii)
      w1r[o * 24 + ii] = W1[(j1 + o) * DD + il * 24 + ii];
  #pragma unroll
  for (int o = 0; o < 4; ++o)
    #pragma unroll
    for (int ii = 0; ii < 8; ++ii)
      w2r[o * 8 + ii] = W2[(j1 + o) * HH + il * 8 + ii];
  #pragma unroll
  for (int o = 0; o < 6; ++o)
    #pragma unroll
    for (int ii = 0; ii < 16; ++ii)
      w3r[o * 16 + ii] = W3[(j3 + o) * HH + il3 * 16 + ii];

  __syncthreads();

  for (int step = 0; step < NSTEP; ++step) {
    const float dt = sh_t[step + 1] - sh_t[step];
    #pragma unroll
    for (int s = 0; s < 4; ++s) {
      // ---- combiner: build MLP input x for this RK stage ----
      if (tid < DD) {
        float y = sh_y[tid];
        float xv;
        if (s == 0)      xv = y;
        else if (s == 1) xv = y + (dt * (1.0f / 3.0f)) * sh_k[0][tid];
        else if (s == 2) xv = y + dt * (sh_k[1][tid] - (1.0f / 3.0f) * sh_k[0][tid]);
        else             xv = y + dt * (sh_k[0][tid] - sh_k[1][tid] + sh_k[2][tid]);
        sh_x[tid] = xv;
      }
      __syncthreads();

      // ---- L1: h1 = relu(W1 x + b1) ----
      {
        float acc[4] = {0.f, 0.f, 0.f, 0.f};
        #pragma unroll
        for (int q = 0; q < 6; ++q) {
          float4 xv = *(const float4*)&sh_x[il * 24 + q * 4];
          float xs[4] = {xv.x, xv.y, xv.z, xv.w};
          #pragma unroll
          for (int e = 0; e < 4; ++e)
            #pragma unroll
            for (int o = 0; o < 4; ++o)
              acc[o] = fmaf(w1r[o * 24 + q * 4 + e], xs[e], acc[o]);
        }
        acc[0] = red16(acc[0]); acc[1] = red16(acc[1]);
        acc[2] = red16(acc[2]); acc[3] = red16(acc[3]);
        if (il == 0) {
          float4 hv;
          hv.x = fmaxf(acc[0] + sh_b1[j1 + 0], 0.f);
          hv.y = fmaxf(acc[1] + sh_b1[j1 + 1], 0.f);
          hv.z = fmaxf(acc[2] + sh_b1[j1 + 2], 0.f);
          hv.w = fmaxf(acc[3] + sh_b1[j1 + 3], 0.f);
          *(float4*)&sh_h1[j1] = hv;
        }
      }
      __syncthreads();

      // ---- L2: h2 = elu(W2 h1 + b2) ----
      {
        float acc[4] = {0.f, 0.f, 0.f, 0.f};
        #pragma unroll
        for (int q = 0; q < 2; ++q) {
          float4 xv = *(const float4*)&sh_h1[il * 8 + q * 4];
          float xs[4] = {xv.x, xv.y, xv.z, xv.w};
          #pragma unroll
          for (int e = 0; e < 4; ++e)
            #pragma unroll
            for (int o = 0; o < 4; ++o)
              acc[o] = fmaf(w2r[o * 8 + q * 4 + e], xs[e], acc[o]);
        }
        acc[0] = red16(acc[0]); acc[1] = red16(acc[1]);
        acc[2] = red16(acc[2]); acc[3] = red16(acc[3]);
        if (il == 0) {
          float4 hv;
          float v0 = acc[0] + sh_b2[j1 + 0]; hv.x = v0 > 0.f ? v0 : expm1f(v0);
          float v1 = acc[1] + sh_b2[j1 + 1]; hv.y = v1 > 0.f ? v1 : expm1f(v1);
          float v2 = acc[2] + sh_b2[j1 + 2]; hv.z = v2 > 0.f ? v2 : expm1f(v2);
          float v3 = acc[3] + sh_b2[j1 + 3]; hv.w = v3 > 0.f ? v3 : expm1f(v3);
          *(float4*)&sh_h2[j1] = hv;
        }
      }
      __syncthreads();

      // ---- L3: k_s = W3 h2 + b3 ----
      {
        float acc[6] = {0.f, 0.f, 0.f, 0.f, 0.f, 0.f};
        #pragma unroll
        for (int q = 0; q < 4; ++q) {
          float4 xv = *(const float4*)&sh_h2[il3 * 16 + q * 4];
          float xs[4] = {xv.x, xv.y, xv.z, xv.w};
          #pragma unroll
          for (int e = 0; e < 4; ++e)
            #pragma unroll
            for (int o = 0; o < 6; ++o)
              acc[o] = fmaf(w3r[o * 16 + q * 4 + e], xs[e], acc[o]);
        }
        #pragma unroll
        for (int o = 0; o < 6; ++o) acc[o] = red8(acc[o]);
        if (il3 == 0) {
          #pragma unroll
          for (int o = 0; o < 6; ++o)
            sh_k[s][j3 + o] = acc[o] + sh_b3[j3 + o];
        }
      }
      __syncthreads();
    } // stages

    // ---- y update + emit coeff for step+1 ----
    if (tid < DD) {
      float y = sh_y[tid];
      y = y + dt * 0.125f *
              (sh_k[0][tid] + 3.f * (sh_k[1][tid] + sh_k[2][tid]) + sh_k[3][tid]);
      sh_y[tid] = y;
      coeffT[(tid % 3) * (KK * NT) + (tid / 3) * NT + (step + 1)] = y;
    }
    __syncthreads();
  }
}

// ---------------- Kernel 2: out[t,m,c,p] = sum_k coeffT[c][k][t]*basis[k,c,p]
// Memory-bound: basis read exactly once (100 MB), out written once (201 MB).
__global__ __launch_bounds__(256, 4) void einsum_kernel(
    const float* __restrict__ basis, const float* __restrict__ coeffT,
    float* __restrict__ out)
{
  __shared__ __align__(16) float sh_c[KK * NT];  // [k][t] for this c, 16KB
  const int tid = threadIdx.x;
  const int bid = blockIdx.x;
  const int c = bid >> 8;        // 0..2
  const int ptile = bid & 255;   // 0..255, 256 pixels each

  const float* cT = coeffT + c * (KK * NT);
  #pragma unroll
  for (int q = 0; q < 4; ++q)
    *(float4*)&sh_c[tid * 16 + q * 4] = *(const float4*)&cT[tid * 16 + q * 4];
  __syncthreads();

  const int slot = tid & 31;   // 32 slots x 8 px = 256 px
  const int tg   = tid >> 5;   // 8 groups x 4 t  = 32 t
  const int px0  = ptile * 256 + slot * 8;
  const float* bp = basis + (size_t)c * NPIX + px0;

  float acc[4][8];
  #pragma unroll
  for (int t = 0; t < 4; ++t)
    #pragma unroll
    for (int p = 0; p < 8; ++p) acc[t][p] = 0.f;

  #pragma unroll 4
  for (int k = 0; k < KK; ++k) {
    const float* bk = bp + (size_t)k * (3 * NPIX);
    float4 b0 = *(const float4*)(bk);
    float4 b1v = *(const float4*)(bk + 4);
    float4 cv = *(const float4*)&sh_c[k * NT + tg * 4];
    float cs[4] = {cv.x, cv.y, cv.z, cv.w};
    float bs[8] = {b0.x, b0.y, b0.z, b0.w, b1v.x, b1v.y, b1v.z, b1v.w};
    #pragma unroll
    for (int t = 0; t < 4; ++t)
      #pragma unroll
      for (int p = 0; p < 8; ++p)
        acc[t][p] = fmaf(cs[t], bs[p], acc[t][p]);
  }

  #pragma unroll
  for (int t = 0; t < 4; ++t) {
    const int tt = tg * 4 + t;
    #pragma unroll
    for (int m = 0; m < MBATCH; ++m) {
      float* op = out + (((size_t)(tt * MBATCH + m) * 3 + c) << 16) + px0;
      *(float4*)(op)     = make_float4(acc[t][0], acc[t][1], acc[t][2], acc[t][3]);
      *(float4*)(op + 4) = make_float4(acc[t][4], acc[t][5], acc[t][6], acc[t][7]);
    }
  }
}

extern "C" void kernel_launch(void* const* d_in, const int* in_sizes, int n_in,
                              void* d_out, int out_size, void* d_ws, size_t ws_size,
                              hipStream_t stream) {
  (void)in_sizes; (void)n_in; (void)out_size; (void)ws_size;
  // setup_inputs order: grid0, t, init_coeffs, W1, b1, W2, b2, W3, b3, basis
  const float* tarr  = (const float*)d_in[1];
  const float* ic    = (const float*)d_in[2];
  const float* W1    = (const float*)d_in[3];
  const float* b1    = (const float*)d_in[4];
  const float* W2    = (const float*)d_in[5];
  const float* b2    = (const float*)d_in[6];
  const float* W3    = (const float*)d_in[7];
  const float* b3    = (const float*)d_in[8];
  const float* basis = (const float*)d_in[9];
  float* coeffT = (float*)d_ws;          // 3*128*32 floats = 48 KB
  float* out    = (float*)d_out;

  hipLaunchKernelGGL(ode_kernel, dim3(1), dim3(512), 0, stream,
                     tarr, ic, W1, b1, W2, b2, W3, b3, coeffT);
  hipLaunchKernelGGL(einsum_kernel, dim3(768), dim3(256), 0, stream,
                     basis, coeffT, out);
}